// Round 23
// baseline (339.977 us; speedup 1.0000x reference)
//
#include <hip/hip_runtime.h>
#include <hip/hip_bf16.h>

#define NTOK 16384
#define HID 7168
#define NEXP 256
#define TOPK 8
#define KSL 256               // k per plane
#define NKZ 28                // planes (7168/256)
#define NIT 32                // 32-token tiles per block (1024 tok)

typedef __bf16 bf16x8 __attribute__((ext_vector_type(8)));
typedef float  f32x16 __attribute__((ext_vector_type(16)));
typedef __attribute__((address_space(1))) const unsigned char ga_t;
typedef __attribute__((address_space(3))) unsigned char la_t;

// Weights bf16 in [kz][ku][e] 16-B-unit layout: unit u = kz*8192 + ku*256 + e
// holds B[e][kz*256 + ku*8 .. +8]  (ku = 0..31, e = 0..255)
__device__ __align__(16) unsigned short g_wb2[NEXP * HID];

__device__ __forceinline__ unsigned int f2bfb(float x) {
    unsigned int u = __float_as_uint(x);
    return (u + 0x7fffu + ((u >> 16) & 1u)) >> 16;
}
__device__ __forceinline__ uint4 pk4(float4 p, float4 q) {
    uint4 u;
    u.x = f2bfb(p.x) | (f2bfb(p.y) << 16);
    u.y = f2bfb(p.z) | (f2bfb(p.w) << 16);
    u.z = f2bfb(q.x) | (f2bfb(q.y) << 16);
    u.w = f2bfb(q.z) | (f2bfb(q.w) << 16);
    return u;
}
__device__ __forceinline__ void gll16(const void* g, void* l) {
    __builtin_amdgcn_global_load_lds((ga_t*)g, (la_t*)l, 16, 0, 0);
}

// wt f32 -> g_wb2. id = kz*8192 + e*32 + ku (src-coalesced; dst 16-B scatter ok)
__global__ void wconv2(const float* __restrict__ wt) {
    const int id = blockIdx.x * 256 + threadIdx.x;   // 0..229375
    const int ku = id & 31;
    const int e  = (id >> 5) & 255;
    const int kz = id >> 13;
    const float* s = wt + (size_t)e * HID + kz * KSL + ku * 8;
    const float4 f0 = *(const float4*)(s);
    const float4 f1 = *(const float4*)(s + 4);
    uint2 o;
    o.x = f2bfb(f0.x) | (f2bfb(f0.y) << 16);
    o.y = f2bfb(f0.z) | (f2bfb(f0.w) << 16);
    uint2 o2;
    o2.x = f2bfb(f1.x) | (f2bfb(f1.y) << 16);
    o2.y = f2bfb(f1.z) | (f2bfb(f1.w) << 16);
    uint4 u = make_uint4(o.x, o.y, o2.x, o2.y);
    ((uint4*)g_wb2)[(size_t)kz * 8192 + (size_t)ku * 256 + e] = u;
}

__global__ void moe_rows(float* __restrict__ ob) {
    const int q = blockIdx.x * 256 + threadIdx.x;
    ob[262144 + q] = (float)((q & 7) * NTOK + (q >> 3));
}

__device__ __forceinline__ void softbar() {
    asm volatile("s_waitcnt lgkmcnt(0)" ::: "memory");
    __builtin_amdgcn_s_barrier();
    __builtin_amdgcn_sched_barrier(0);
}

// grid (16, 28); 512 thr = 8 waves. LDS: B slice 128 KB @0, A tile 16 KB @131072.
// B staged ONCE; loop stages only A (v15 cadence). Partials bf16 -> pw[kz][tok][e].
__global__ __launch_bounds__(512, 1) void moe_gate_v23(
    const float* __restrict__ hs,
    unsigned short* __restrict__ pw)
{
    __shared__ __align__(16) char smem[147456];

    const int tid   = threadIdx.x;
    const int lane  = tid & 63;
    const int l31   = lane & 31;
    const int khalf = lane >> 5;
    const int w     = tid >> 6;          // 0..7 = expert group (32 exps)
    const int t0    = blockIdx.x * 1024;
    const int kz    = blockIdx.y;

    // ---- B slice -> LDS once (linear gll, 16 units/thread) ----
    {
        const char* bsrc = (const char*)g_wb2 + (size_t)kz * 131072;
        #pragma unroll
        for (int j = 0; j < 16; ++j)
            gll16(bsrc + (size_t)(tid + j * 512) * 16, smem + (tid + j * 512) * 16);
    }
    __syncthreads();                     // full drain once: B resident

    // ---- A staging map (thread: token row r, 16-f32 chunk kc) ----
    const int r  = tid >> 4;             // 0..31
    const int kc = tid & 15;             // 0..15
    const float* aptr = hs + (size_t)(t0 + r) * HID + kz * KSL + kc * 16;
    const int awb0 = 131072 + (2 * kc) * 512 + r * 16;
    const int awb1 = awb0 + 512;

    // ---- fragment read bases ----
    const int abase = 131072 + l31 * 16;         // + (2s+khalf)*512
    const int bbase = (w * 32 + l31) * 16;       // + (2s+khalf)*4096

    float4 fa0, fa1, fa2, fa3;           // A reg set A
    float4 fb0, fb1, fb2, fb3;           // A reg set B

#define LOADA(S, IT)                                                          \
    do {                                                                      \
        const float* p = aptr + (size_t)(IT) * 32 * HID;                      \
        f##S##0 = *(const float4*)(p);                                        \
        f##S##1 = *(const float4*)(p + 4);                                    \
        f##S##2 = *(const float4*)(p + 8);                                    \
        f##S##3 = *(const float4*)(p + 12);                                   \
    } while (0)

#define WRITEA(S)                                                             \
    do {                                                                      \
        *(uint4*)(smem + awb0) = pk4(f##S##0, f##S##1);                       \
        *(uint4*)(smem + awb1) = pk4(f##S##2, f##S##3);                       \
    } while (0)

#define TILE(ACC)                                                             \
    do {                                                                      \
        _Pragma("unroll")                                                     \
        for (int s = 0; s < 16; ++s) {                                        \
            const int ku = 2 * s + khalf;                                     \
            bf16x8 a = *(const bf16x8*)(smem + abase + ku * 512);             \
            bf16x8 b = *(const bf16x8*)(smem + bbase + ku * 4096);            \
            ACC = __builtin_amdgcn_mfma_f32_32x32x16_bf16(a, b, ACC, 0, 0, 0);\
        }                                                                     \
    } while (0)

#define STOREP(ACC, IT)                                                       \
    do {                                                                      \
        _Pragma("unroll")                                                     \
        for (int q = 0; q < 16; ++q) {                                        \
            const float o = __shfl_xor(ACC[q], 1);                            \
            if (!(lane & 1)) {                                                \
                const unsigned int v = f2bfb(ACC[q]) | (f2bfb(o) << 16);      \
                const int tokl = (q & 3) + 8 * (q >> 2) + 4 * khalf;          \
                ((unsigned int*)pw)[(size_t)kz * 2097152                      \
                    + (size_t)(t0 + (IT) * 32 + tokl) * 128                   \
                    + ((w * 32 + l31) >> 1)] = v;                             \
            }                                                                 \
        }                                                                     \
    } while (0)

    // ---- prologue ----
    LOADA(a, 0);
    WRITEA(a);
    softbar();

    // ---- main loop: x2 unrolled, A 1-ahead ----
    for (int it = 0; it < NIT; it += 2) {
        // tile it (A in LDS from set a)
        LOADA(b, it + 1);
        {
            f32x16 acc = {};
            TILE(acc);
            STOREP(acc, it);
        }
        softbar();                 // A reads drained
        WRITEA(b);
        softbar();                 // A(it+1) visible

        // tile it+1
        if (it + 2 < NIT) LOADA(a, it + 2);
        {
            f32x16 acc = {};
            TILE(acc);
            STOREP(acc, it + 1);
        }
        softbar();
        if (it + 2 < NIT) {
            WRITEA(a);
            softbar();
        }
    }
#undef LOADA
#undef WRITEA
#undef TILE
#undef STOREP
}

// ---- reduce: sum 28 bf16 planes, top-8 + renormalized softmax ----
__global__ __launch_bounds__(256) void moe_reduce2(
    const unsigned short* __restrict__ pw,
    float* __restrict__ ob)
{
    __shared__ float ll[64 * 257];
    const int tid = threadIdx.x;
    const size_t ro = (size_t)blockIdx.x * 16384;    // 64 tok x 256 exp elems

    #pragma unroll
    for (int j = 0; j < 16; ++j) {
        const int f = j * 1024 + tid * 4;
        float4 v = make_float4(0.f, 0.f, 0.f, 0.f);
        #pragma unroll
        for (int kzi = 0; kzi < NKZ; ++kzi) {
            const uint2 u = *(const uint2*)(pw + (size_t)kzi * 4194304 + ro + f);
            v.x += __uint_as_float((u.x & 0xffffu) << 16);
            v.y += __uint_as_float(u.x & 0xffff0000u);
            v.z += __uint_as_float((u.y & 0xffffu) << 16);
            v.w += __uint_as_float(u.y & 0xffff0000u);
        }
        const int t = f >> 8;
        const int e = f & 255;
        *(float4*)&ll[t * 257 + e] = v;
    }
    __syncthreads();

    if (tid < 64) {
        const float* lr = ll + tid * 257;
        float bv[TOPK]; int bi8[TOPK];
        #pragma unroll
        for (int k = 0; k < TOPK; ++k) { bv[k] = -1e30f; bi8[k] = 0; }
        for (int e = 0; e < NEXP; ++e) {
            const float v = lr[e];
            if (v > bv[TOPK - 1]) {
                int k = TOPK - 1;
                while (k > 0 && v > bv[k - 1]) {
                    bv[k] = bv[k - 1]; bi8[k] = bi8[k - 1]; --k;
                }
                bv[k] = v; bi8[k] = e;      // strict > : ties keep lower idx
            }
        }
        float ev[TOPK], ssum = 0.f;
        #pragma unroll
        for (int q = 0; q < TOPK; ++q) { ev[q] = expf(bv[q] - bv[0]); ssum += ev[q]; }
        const float inv = 1.0f / ssum;

        const int tg = blockIdx.x * 64 + tid;
        #pragma unroll
        for (int q = 0; q < TOPK; ++q) {
            ob[(size_t)tg * TOPK + q]          = (float)bi8[q];   // idx
            ob[131072 + (size_t)tg * TOPK + q] = ev[q] * inv;     // weight
        }
    }
}

extern "C" void kernel_launch(void* const* d_in, const int* in_sizes, int n_in,
                              void* d_out, int out_size, void* d_ws, size_t ws_size,
                              hipStream_t stream) {
    const float* hs = (const float*)d_in[0];   // [16384, 7168] f32
    const float* wt = (const float*)d_in[1];   // [256, 7168] f32
    float* ob = (float*)d_out;                 // f32[393216]: idx | weight | row
    unsigned short* pw = (unsigned short*)d_ws;   // 28 x [16384][256] bf16 = 235 MB
    // ws_size observed 1.79 GB every round (fillBuffer 1835008 KB) >> 235 MB.

    wconv2<<<dim3(NEXP * HID / 8 / 256), dim3(256), 0, stream>>>(wt);
    moe_gate_v23<<<dim3(16, NKZ), dim3(512), 0, stream>>>(hs, pw);
    moe_reduce2<<<dim3(256), dim3(256), 0, stream>>>(pw, ob);
    moe_rows<<<dim3(512), dim3(256), 0, stream>>>(ob);
}

// Round 24
// 242.521 us; speedup vs baseline: 1.4018x; 1.4018x over previous
//
#include <hip/hip_runtime.h>
#include <hip/hip_bf16.h>

#define NTOK 16384
#define HID 7168
#define NEXP 256
#define TOPK 8

#define BT 32                  // tokens per block
#define NIT 112                // K iterations (BK=64)

typedef __bf16 bf16x8 __attribute__((ext_vector_type(8)));
typedef float  f32x16 __attribute__((ext_vector_type(16)));

// Weights, MFMA-fragment-linear (R12-proven layout):
// uint4 idx = ((p8*8 + g)*8 + ks)*64 + lane holds
// B[e = g*32 + (lane&31)][k = p8*128 + ks*16 + (lane>>5)*8 .. +8]
__device__ __align__(16) unsigned short g_wb[NEXP * HID];

__device__ __forceinline__ unsigned int f2bfb(float x) {
    unsigned int u = __float_as_uint(x);
    return (u + 0x7fffu + ((u >> 16) & 1u)) >> 16;
}
__device__ __forceinline__ uint4 pk4(float4 p, float4 q) {
    uint4 u;
    u.x = f2bfb(p.x) | (f2bfb(p.y) << 16);
    u.y = f2bfb(p.z) | (f2bfb(p.w) << 16);
    u.z = f2bfb(q.x) | (f2bfb(q.y) << 16);
    u.w = f2bfb(q.z) | (f2bfb(q.w) << 16);
    return u;
}
__device__ __forceinline__ bf16x8 asbf8(uint4 u) {
    union { uint4 a; bf16x8 b; } c; c.a = u; return c.b;
}

__global__ void wconv_frag(const float* __restrict__ wt) {
    const int tid = blockIdx.x * 256 + threadIdx.x;
    const int l  = tid & 63;
    const int ks = (tid >> 6) & 7;
    const int g  = (tid >> 9) & 7;
    const int p  = tid >> 12;
    const int e  = g * 32 + (l & 31);
    const int kb = p * 128 + ks * 16 + ((l >> 5) << 3);
    const float4* s = (const float4*)(wt + (size_t)e * HID + kb);
    ((uint4*)g_wb)[tid] = pk4(s[0], s[1]);
}

__global__ void moe_rows(float* __restrict__ ob) {
    const int q = blockIdx.x * 256 + threadIdx.x;
    ob[262144 + q] = (float)((q & 7) * NTOK + (q >> 3));
}

// Block 512 thr = 8 waves; wave w: 32 tokens x experts [w*32, w*32+32).
// A: LDS bf16 tri-buffer 3 x 4 KB (async-split staging). B: regs from g_wb.
// LDS 33.8 KB; epilogue aliases logits [32][257] f32 over it.
__global__ __launch_bounds__(512, 4) void moe_gate_v15(
    const float* __restrict__ hs,
    float* __restrict__ ob)
{
    __shared__ __align__(16) char smem[33792];

    const int tid   = threadIdx.x;
    const int lane  = tid & 63;
    const int w     = tid >> 6;       // 0..7 = expert group
    const int khalf = lane >> 5;
    const int t0    = blockIdx.x * BT;

    // A staging: thread loads hs[t0 + (tid>>4)][s*64 + (tid&15)*4 .. +4]
    const int ar = tid >> 4;          // 0..31
    const int ac = tid & 15;          // 0..15
    const float* aload = hs + (size_t)(t0 + ar) * HID + ac * 4;
    const int awb = (ac >> 1) * 512 + ar * 16 + (ac & 1) * 8;   // bf16 dest byte

    // A fragment read: conflict-free contiguous (lanes 0..31 adjacent 16B)
    const int arb = (lane & 31) * 16;

    // B fragment-linear base for this wave's expert group
    const char* const bbase = (const char*)g_wb + w * 8192 + lane * 16;

    f32x16 acc = {};
    uint4 bA0, bA1, bA2, bA3;   // B set A
    uint4 bB0, bB1, bB2, bB3;   // B set B

    char* p0 = smem;            // read buf (iter s)
    char* p1 = smem + 4096;     // iter s+1
    char* p2 = smem + 8192;     // write target (iter s+2)

#define LOADB(SET, S)                                                         \
    do {                                                                      \
        const char* bp = bbase + (size_t)((S) >> 1) * 65536 + ((S) & 1) * 4096; \
        b##SET##0 = *(const uint4*)(bp);                                      \
        b##SET##1 = *(const uint4*)(bp + 1024);                               \
        b##SET##2 = *(const uint4*)(bp + 2048);                               \
        b##SET##3 = *(const uint4*)(bp + 3072);                               \
    } while (0)

#define WRITEA(V, BUF)                                                        \
    do {                                                                      \
        uint2 u;                                                              \
        u.x = f2bfb((V).x) | (f2bfb((V).y) << 16);                            \
        u.y = f2bfb((V).z) | (f2bfb((V).w) << 16);                            \
        *(uint2*)((BUF) + awb) = u;                                           \
    } while (0)

#define COMPUTE(BUF, SET)                                                     \
    do {                                                                      \
        bf16x8 a;                                                             \
        a = *(const bf16x8*)((BUF) + (0 * 2 + khalf) * 512 + arb);            \
        acc = __builtin_amdgcn_mfma_f32_32x32x16_bf16(a, asbf8(b##SET##0), acc, 0, 0, 0); \
        a = *(const bf16x8*)((BUF) + (1 * 2 + khalf) * 512 + arb);            \
        acc = __builtin_amdgcn_mfma_f32_32x32x16_bf16(a, asbf8(b##SET##1), acc, 0, 0, 0); \
        a = *(const bf16x8*)((BUF) + (2 * 2 + khalf) * 512 + arb);            \
        acc = __builtin_amdgcn_mfma_f32_32x32x16_bf16(a, asbf8(b##SET##2), acc, 0, 0, 0); \
        a = *(const bf16x8*)((BUF) + (3 * 2 + khalf) * 512 + arb);            \
        acc = __builtin_amdgcn_mfma_f32_32x32x16_bf16(a, asbf8(b##SET##3), acc, 0, 0, 0); \
    } while (0)

    // ---- prologue: A(0)->p0, A(1)->p1, B(0)->setA ----
    {
        float4 v0 = *(const float4*)(aload);
        float4 v1 = *(const float4*)(aload + 64);
        WRITEA(v0, p0);
        WRITEA(v1, p1);
    }
    LOADB(A, 0);
    __syncthreads();

    // ---- main loop: x2 unrolled; 1 sync/iter; A 2-ahead, B 1-ahead ----
    for (int s = 0; s < NIT; s += 2) {
        // iter s (read p0, set A)
        float4 vA;
        const bool ldA = (s + 2 < NIT);
        if (ldA) vA = *(const float4*)(aload + (size_t)(s + 2) * 64);
        LOADB(B, s + 1);
        COMPUTE(p0, A);
        __syncthreads();
        if (ldA) WRITEA(vA, p2);

        // iter s+1 (read p1, set B)
        float4 vB;
        const bool ldB = (s + 3 < NIT);
        if (ldB) vB = *(const float4*)(aload + (size_t)(s + 3) * 64);
        if (s + 2 < NIT) LOADB(A, s + 2);
        COMPUTE(p1, B);
        __syncthreads();
        if (ldB) WRITEA(vB, p0);

        // rotate: (p0,p1,p2) <- (p2,p0,p1)
        char* t = p2; p2 = p1; p1 = p0; p0 = t;
    }

    // ---- epilogue: logits [32][257] f32 aliased over smem ----
    float* ll = (float*)smem;
    {
        const int ec = w * 32 + (lane & 31);
        #pragma unroll
        for (int r = 0; r < 16; ++r) {
            const int tok = (r & 3) + 8 * (r >> 2) + 4 * khalf;
            ll[tok * 257 + ec] = acc[r];
        }
    }
    __syncthreads();

    if (tid < BT) {
        const float* lr = ll + tid * 257;
        float bv[TOPK]; int bi8[TOPK];
        #pragma unroll
        for (int k = 0; k < TOPK; ++k) { bv[k] = -1e30f; bi8[k] = 0; }
        for (int e = 0; e < NEXP; ++e) {
            const float v = lr[e];
            if (v > bv[TOPK - 1]) {
                int k = TOPK - 1;
                while (k > 0 && v > bv[k - 1]) {
                    bv[k] = bv[k - 1]; bi8[k] = bi8[k - 1]; --k;
                }
                bv[k] = v; bi8[k] = e;      // strict > : ties keep lower idx
            }
        }
        float ev[TOPK], ssum = 0.f;
        #pragma unroll
        for (int r = 0; r < TOPK; ++r) { ev[r] = expf(bv[r] - bv[0]); ssum += ev[r]; }
        const float inv = 1.0f / ssum;

        const int tg = t0 + tid;
        #pragma unroll
        for (int r = 0; r < TOPK; ++r) {
            ob[(size_t)tg * TOPK + r]          = (float)bi8[r];   // idx
            ob[131072 + (size_t)tg * TOPK + r] = ev[r] * inv;     // weight
        }
    }
#undef LOADB
#undef WRITEA
#undef COMPUTE
}

extern "C" void kernel_launch(void* const* d_in, const int* in_sizes, int n_in,
                              void* d_out, int out_size, void* d_ws, size_t ws_size,
                              hipStream_t stream) {
    const float* hs = (const float*)d_in[0];   // [16384, 7168] f32
    const float* wt = (const float*)d_in[1];   // [256, 7168] f32
    float* ob = (float*)d_out;                 // f32[393216]: idx | weight | row

    wconv_frag<<<dim3(NEXP * HID / 8 / 256), dim3(256), 0, stream>>>(wt);
    moe_gate_v15<<<dim3(NTOK / BT), dim3(512), 0, stream>>>(hs, ob);
    moe_rows<<<dim3(512), dim3(256), 0, stream>>>(ob);
}